// Round 1
// 313.990 us; speedup vs baseline: 1.0728x; 1.0728x over previous
//
#include <hip/hip_runtime.h>
#include <hip/hip_fp16.h>

#define NFEAT 128
#define NHID 64
#define MAXB 1024          // max dst buckets (node>>8), supports N<=262144
#define BSHIFT 8
#define BNODES 256
#define PBLK 512           // partition/hist blocks

typedef _Float16 f16x8 __attribute__((ext_vector_type(8)));
typedef float f32x4 __attribute__((ext_vector_type(4)));

// ---------- edge-index dtype detection + W1 transpose/convert ----------
// JAX reference says int64 but default JAX config downcasts to int32.
// Little-endian int64 with values < 2^31 => every odd int32 word is 0.
__global__ void k_detect(const int* __restrict__ ei_words, int nwords, int* flag,
                         const float* __restrict__ W1, __half* __restrict__ w1t) {
    __shared__ int s_or;
    if (threadIdx.x == 0) s_or = 0;
    __syncthreads();
    int acc = 0;
    for (int i = 1 + 2 * (int)threadIdx.x; i < nwords; i += 2 * (int)blockDim.x)
        acc |= ei_words[i];
    atomicOr(&s_or, acc);
    // W1[128][64] fp32 -> w1t[64][128] fp16 (coalesced writes)
    for (int i = threadIdx.x; i < NFEAT * NHID; i += 256) {
        int n = i >> 7, k = i & 127;
        w1t[i] = __float2half(W1[k * NHID + n]);
    }
    __syncthreads();
    if (threadIdx.x == 0) *flag = (s_or == 0) ? 1 : 0;
}

__device__ __forceinline__ int edge_idx(const int* __restrict__ ei, int is64,
                                        long long E, long long e, int which) {
    long long pos = which ? (E + e) : e;
    return is64 ? ei[2 * pos] : ei[pos];
}

// ---------- bucket histogram (contiguous chunks; saves per-block hist) ----------
__global__ __launch_bounds__(256) void k_bhist(const int* __restrict__ ei,
                                               const int* __restrict__ flag,
                                               long long E, int* gbhist,
                                               int* __restrict__ blockhist,
                                               int NB, long long perblk) {
    __shared__ int hist[MAXB];
    for (int i = threadIdx.x; i < NB; i += 256) hist[i] = 0;
    __syncthreads();
    int is64 = *flag;
    long long lo = (long long)blockIdx.x * perblk;
    long long hi = lo + perblk; if (hi > E) hi = E;
    for (long long e = lo + threadIdx.x; e < hi; e += 256) {
        int d = edge_idx(ei, is64, E, e, 1);
        atomicAdd(&hist[d >> BSHIFT], 1);
    }
    __syncthreads();
    int* bh = blockhist + (size_t)blockIdx.x * MAXB;
    for (int i = threadIdx.x; i < NB; i += 256) {
        int v = hist[i];
        bh[i] = v;
        if (v) atomicAdd(&gbhist[i], v);
    }
}

// ---------- scan bucket totals (1 block); also writes off[N]=E ----------
__global__ __launch_bounds__(256) void k_bscan(const int* __restrict__ gbhist, int NB,
                                               int* boff, int* bcur, int* offN) {
    __shared__ int s[256];
    int t = threadIdx.x;
    int v[4]; int sum = 0;
#pragma unroll
    for (int j = 0; j < 4; ++j) {
        int i = t * 4 + j;
        v[j] = (i < NB) ? gbhist[i] : 0;
        sum += v[j];
    }
    s[t] = sum;
    __syncthreads();
    for (int d = 1; d < 256; d <<= 1) {
        int val = (t >= d) ? s[t - d] : 0;
        __syncthreads();
        s[t] += val;
        __syncthreads();
    }
    int run = s[t] - sum;   // exclusive
#pragma unroll
    for (int j = 0; j < 4; ++j) {
        int i = t * 4 + j;
        if (i <= NB) boff[i] = run;
        if (i < NB)  bcur[i] = run;
        run += v[j];
    }
    if (t == 255) *offN = s[255];   // off[N] = E
}

// ---------- partition edges into dst buckets (reuses blockhist; 1 edge pass) ----------
// record = src | (dst&255)<<24  (requires src < 2^24)
__global__ __launch_bounds__(256) void k_partition(const int* __restrict__ ei,
                                                   const int* __restrict__ flag,
                                                   long long E, int* bcur,
                                                   const int* __restrict__ blockhist,
                                                   unsigned* __restrict__ staging,
                                                   int NB, long long perblk) {
    __shared__ int cur[MAXB];
    const int* bh = blockhist + (size_t)blockIdx.x * MAXB;
    for (int i = threadIdx.x; i < NB; i += 256) {
        int v = bh[i];
        cur[i] = v ? atomicAdd(&bcur[i], v) : 0;
    }
    __syncthreads();
    long long lo = (long long)blockIdx.x * perblk;
    long long hi = lo + perblk; if (hi > E) hi = E;
    int is64 = *flag;
    for (long long e = lo + threadIdx.x; e < hi; e += 256) {
        int s = edge_idx(ei, is64, E, e, 0);
        int d = edge_idx(ei, is64, E, e, 1);
        int pos = atomicAdd(&cur[d >> BSHIFT], 1);
        staging[pos] = (unsigned)s | ((unsigned)(d & (BNODES - 1)) << 24);
    }
}

// ---------- per-bucket CSR: node counts, scan, fill esrc; emit off & dinv ----------
__global__ __launch_bounds__(256) void k_bucket(const unsigned* __restrict__ staging,
                                                const int* __restrict__ boff,
                                                int N, int* off, int* esrc, float* dinv) {
    __shared__ int cnt_s[BNODES];
    __shared__ int scan_s[BNODES];
    int b = blockIdx.x;
    int base = b << BSHIFT;
    int t = threadIdx.x;
    cnt_s[t] = 0;
    __syncthreads();
    int lo = boff[b], hi = boff[b + 1];
    for (int e = lo + t; e < hi; e += 256)
        atomicAdd(&cnt_s[staging[e] >> 24], 1);
    __syncthreads();
    int v = cnt_s[t];
    scan_s[t] = v;
    __syncthreads();
    for (int d = 1; d < 256; d <<= 1) {
        int val = (t >= d) ? scan_s[t - d] : 0;
        __syncthreads();
        scan_s[t] += val;
        __syncthreads();
    }
    int excl = scan_s[t] - v;
    int node = base + t;
    if (node < N) {
        off[node] = lo + excl;
        dinv[node] = rsqrtf((float)v + 1.0f);   // +1 self loop
    }
    __syncthreads();
    cnt_s[t] = lo + excl;   // reuse as cursor
    __syncthreads();
    for (int e = lo + t; e < hi; e += 256) {
        unsigned sd = staging[e];
        int pos = atomicAdd(&cnt_s[sd >> 24], 1);
        esrc[pos] = (int)(sd & 0xFFFFFFu);
    }
}

// ---------- LDS XOR-swizzle: row stride 256 B, spread 8 rows over 8 16B slots ----------
__device__ __forceinline__ int swz(int row, int byteoff) {
    return (row << 8) + (byteoff ^ ((row & 7) << 4));
}

// ---------- GEMM1 (MFMA): x[N,128]fp32 @ W1t -> dinv[row]*out, fp16 xw1s[N,64] ----------
// Swapped operands: A = W1t tile (cols as M), B = x tile (rows as N) so each lane
// owns one output row -> scalar dinv + packed 8B stores. A/B both loaded as
// 8-contiguous-K fragments; identical K-mapping on both sides cancels any internal
// K permutation. C/D mapping (HW-verified): col=lane&15, row=(lane>>4)*4+reg.
__global__ __launch_bounds__(256) void k_gemm1(const float* __restrict__ x,
                                               const __half* __restrict__ w1t,
                                               const float* __restrict__ dinv,
                                               __half* __restrict__ xw1s, int N) {
    __shared__ __align__(16) __half xs[64 * NFEAT];  // 16 KB, swizzled
    __shared__ __align__(16) __half ws[NHID * NFEAT]; // 16 KB, swizzled
    int t = threadIdx.x;
    // stage W1t [64][128] fp16 (16B chunks)
    for (int i = t; i < NHID * NFEAT / 8; i += 256) {
        int row = i >> 4, c16 = (i & 15) << 4;
        uint4 v = ((const uint4*)w1t)[i];
        *(uint4*)((char*)ws + swz(row, c16)) = v;
    }
    int row0 = blockIdx.x * 64;
    // stage x tile 64x128 fp32 -> fp16 (8B chunks)
    for (int i = t; i < 64 * 32; i += 256) {
        int r = i >> 5, c4 = i & 31;
        int row = row0 + r;
        float4 v = (row < N) ? ((const float4*)x)[(size_t)row * 32 + c4]
                             : make_float4(0.f, 0.f, 0.f, 0.f);
        __half2 h0 = __floats2half2_rn(v.x, v.y);
        __half2 h1 = __floats2half2_rn(v.z, v.w);
        uint2 p = make_uint2(*(unsigned*)&h0, *(unsigned*)&h1);
        *(uint2*)((char*)xs + swz(r, c4 * 8)) = p;
    }
    __syncthreads();
    int wave = t >> 6, lane = t & 63;
    int lr = lane & 15, g = lane >> 4;
    int xrow = wave * 16 + lr;                 // this lane's output row (within tile)
    f16x8 xb[4];
#pragma unroll
    for (int kc = 0; kc < 4; ++kc)
        xb[kc] = *(const f16x8*)((const char*)xs + swz(xrow, kc * 64 + g * 16));
    int row = row0 + xrow;
    float di = (row < N) ? dinv[row] : 0.f;
#pragma unroll
    for (int c = 0; c < 4; ++c) {
        f32x4 acc = {0.f, 0.f, 0.f, 0.f};
#pragma unroll
        for (int kc = 0; kc < 4; ++kc) {
            f16x8 a = *(const f16x8*)((const char*)ws + swz(c * 16 + lr, kc * 64 + g * 16));
            acc = __builtin_amdgcn_mfma_f32_16x16x32_f16(a, xb[kc], acc, 0, 0, 0);
        }
        if (row < N) {
            __half2 o0 = __floats2half2_rn(di * acc[0], di * acc[1]);
            __half2 o1 = __floats2half2_rn(di * acc[2], di * acc[3]);
            uint2 p = make_uint2(*(unsigned*)&o0, *(unsigned*)&o1);
            *(uint2*)&xw1s[(size_t)row * NHID + c * 16 + g * 4] = p;
        }
    }
}

// ---------- 8-lane gather: lane group g=lane>>3 handles edge e+g; li=lane&7 ----------
// Each lane loads a uint4 (8 fp16) = 1/8 row; one instruction = 8 rows = 8 lines.
__device__ __forceinline__ void addhalf8(float2 (&acc)[4], uint4 p) {
    const __half2* hh = (const __half2*)&p;
#pragma unroll
    for (int j = 0; j < 4; ++j) {
        float2 v = __half22float2(hh[j]);
        acc[j].x += v.x; acc[j].y += v.y;
    }
}

__device__ __forceinline__ void gather_node8(const int* __restrict__ off,
                                             const int* __restrict__ esrc,
                                             const uint4* __restrict__ feat4,
                                             int d, int g, int li, float2 (&acc)[4]) {
#pragma unroll
    for (int j = 0; j < 4; ++j) acc[j] = make_float2(0.f, 0.f);
    int lo = off[d], hi = off[d + 1];
    int e = lo;
    for (; e + 16 <= hi; e += 16) {
        int s0 = esrc[e + g];
        int s1 = esrc[e + 8 + g];
        uint4 p0 = feat4[(size_t)s0 * 8 + li];
        uint4 p1 = feat4[(size_t)s1 * 8 + li];
        addhalf8(acc, p0);
        addhalf8(acc, p1);
    }
    for (; e + 8 <= hi; e += 8) {
        uint4 p0 = feat4[(size_t)esrc[e + g] * 8 + li];
        addhalf8(acc, p0);
    }
    int rem = hi - e;
    if (g < rem) {
        uint4 p0 = feat4[(size_t)esrc[e + g] * 8 + li];
        addhalf8(acc, p0);
    }
    // reduce across the 8 groups (lanes differing in bits 3..5)
#pragma unroll
    for (int m = 8; m <= 32; m <<= 1) {
#pragma unroll
        for (int j = 0; j < 4; ++j) {
            acc[j].x += __shfl_xor(acc[j].x, m);
            acc[j].y += __shfl_xor(acc[j].y, m);
        }
    }
}

// ---------- layer-1 aggregation: bias+relu, output pre-scaled fp16 h ----------
__global__ __launch_bounds__(256) void k_agg1(const int* __restrict__ off,
                                              const int* __restrict__ esrc,
                                              const float* __restrict__ dinv,
                                              const uint4* __restrict__ xw1s4,
                                              const float* __restrict__ b1,
                                              uint4* __restrict__ h4, int N) {
    int wave = threadIdx.x >> 6;
    int lane = threadIdx.x & 63;
    int d = blockIdx.x * 4 + wave;
    if (d >= N) return;
    int g = lane >> 3, li = lane & 7;
    float2 acc[4];
    gather_node8(off, esrc, xw1s4, d, g, li, acc);
    if (g == 0) {
        uint4 sp = xw1s4[(size_t)d * 8 + li];   // self loop (pre-scaled)
        addhalf8(acc, sp);
        float dd = dinv[d];
        float4 bA = ((const float4*)b1)[li * 2 + 0];
        float4 bB = ((const float4*)b1)[li * 2 + 1];
        float v0 = fmaxf(dd * acc[0].x + bA.x, 0.f);
        float v1 = fmaxf(dd * acc[0].y + bA.y, 0.f);
        float v2 = fmaxf(dd * acc[1].x + bA.z, 0.f);
        float v3 = fmaxf(dd * acc[1].y + bA.w, 0.f);
        float v4 = fmaxf(dd * acc[2].x + bB.x, 0.f);
        float v5 = fmaxf(dd * acc[2].y + bB.y, 0.f);
        float v6 = fmaxf(dd * acc[3].x + bB.z, 0.f);
        float v7 = fmaxf(dd * acc[3].y + bB.w, 0.f);
        __half2 o[4];
        o[0] = __floats2half2_rn(dd * v0, dd * v1);   // pre-scaled for layer 2
        o[1] = __floats2half2_rn(dd * v2, dd * v3);
        o[2] = __floats2half2_rn(dd * v4, dd * v5);
        o[3] = __floats2half2_rn(dd * v6, dd * v7);
        h4[(size_t)d * 8 + li] = *(const uint4*)o;
    }
}

// ---------- layer-2 aggregation: fp16 in -> fp32 agg2 ----------
__global__ __launch_bounds__(256) void k_agg2(const int* __restrict__ off,
                                              const int* __restrict__ esrc,
                                              const float* __restrict__ dinv,
                                              const uint4* __restrict__ h4,
                                              float* __restrict__ agg2, int N) {
    int wave = threadIdx.x >> 6;
    int lane = threadIdx.x & 63;
    int d = blockIdx.x * 4 + wave;
    if (d >= N) return;
    int g = lane >> 3, li = lane & 7;
    float2 acc[4];
    gather_node8(off, esrc, h4, d, g, li, acc);
    if (g == 0) {
        uint4 sp = h4[(size_t)d * 8 + li];   // self loop (pre-scaled)
        addhalf8(acc, sp);
        float dd = dinv[d];
        float4* row = (float4*)&agg2[(size_t)d * NHID];
        row[li * 2 + 0] = make_float4(dd * acc[0].x, dd * acc[0].y, dd * acc[1].x, dd * acc[1].y);
        row[li * 2 + 1] = make_float4(dd * acc[2].x, dd * acc[2].y, dd * acc[3].x, dd * acc[3].y);
    }
}

// ---------- register-blocked fp32 GEMM helper ----------
__device__ __forceinline__ void fma4(float (&acc)[4], float a, const float4& b) {
    acc[0] += a * b.x; acc[1] += a * b.y; acc[2] += a * b.z; acc[3] += a * b.w;
}

// ---------- GEMM2: agg2[N,64] @ W2[64,128] + b2 -> out[N,128] ----------
__global__ __launch_bounds__(256) void k_gemm2(const float* __restrict__ h,
                                               const float* __restrict__ W2,
                                               const float* __restrict__ b2,
                                               float* __restrict__ out, int N, int ntiles) {
    __shared__ float sB[NHID * NFEAT]; // 32 KB
    __shared__ float sA[64 * NHID];    // 16 KB
    for (int i = threadIdx.x; i < NHID * NFEAT / 4; i += 256)
        ((float4*)sB)[i] = ((const float4*)W2)[i];
    int rg = threadIdx.x >> 5;
    int cg = threadIdx.x & 31;
    int c0 = cg * 4;
    float4 bias = *(const float4*)&b2[c0];
    for (int tile = blockIdx.x; tile < ntiles; tile += gridDim.x) {
        int row0 = tile * 64;
        __syncthreads();
        for (int i = threadIdx.x; i < 64 * NHID / 4; i += 256) {
            int r = i >> 4, c4 = i & 15;
            int row = row0 + r;
            ((float4*)sA)[i] = (row < N) ? ((const float4*)h)[(long long)row * 16 + c4]
                                         : make_float4(0.f, 0.f, 0.f, 0.f);
        }
        __syncthreads();
        float acc[8][4] = {};
#pragma unroll 2
        for (int k = 0; k < NHID; k += 4) {
            float4 b0 = *(const float4*)&sB[(k + 0) * NFEAT + c0];
            float4 b1v = *(const float4*)&sB[(k + 1) * NFEAT + c0];
            float4 b2f = *(const float4*)&sB[(k + 2) * NFEAT + c0];
            float4 b3 = *(const float4*)&sB[(k + 3) * NFEAT + c0];
#pragma unroll
            for (int r = 0; r < 8; ++r) {
                float4 a = *(const float4*)&sA[(rg * 8 + r) * NHID + k];
                fma4(acc[r], a.x, b0); fma4(acc[r], a.y, b1v);
                fma4(acc[r], a.z, b2f); fma4(acc[r], a.w, b3);
            }
        }
#pragma unroll
        for (int r = 0; r < 8; ++r) {
            int row = row0 + rg * 8 + r;
            if (row < N) {
                float4 o = make_float4(acc[r][0] + bias.x, acc[r][1] + bias.y,
                                       acc[r][2] + bias.z, acc[r][3] + bias.w);
                *(float4*)&out[(long long)row * NFEAT + c0] = o;
            }
        }
    }
}

static inline char* align256(char* p) {
    return (char*)(((uintptr_t)p + 255) & ~(uintptr_t)255);
}

extern "C" void kernel_launch(void* const* d_in, const int* in_sizes, int n_in,
                              void* d_out, int out_size, void* d_ws, size_t ws_size,
                              hipStream_t stream) {
    const float* x  = (const float*)d_in[0];
    const int*   ei = (const int*)d_in[1];
    const float* W1 = (const float*)d_in[2];
    const float* b1 = (const float*)d_in[3];
    const float* W2 = (const float*)d_in[4];
    const float* b2 = (const float*)d_in[5];
    float* out = (float*)d_out;

    const int N = in_sizes[0] / NFEAT;            // 100000
    const long long E = in_sizes[1] / 2;          // 1600000
    const int NB = (N + BNODES - 1) >> BSHIFT;    // 391 buckets

    // workspace layout (each region 256B-aligned where it matters)
    char* w = (char*)d_ws;
    int*      flag      = (int*)w;                        // pad 256 B
    int*      gbhist    = (int*)(w + 256);                // MAXB
    int*      boff      = gbhist + MAXB;                  // MAXB+1
    int*      bcur      = boff + MAXB + 1;                // MAXB
    int*      blockhist = bcur + MAXB;                    // PBLK*MAXB (2 MB)
    float*    dinv      = (float*)(blockhist + (size_t)PBLK * MAXB);  // N
    int*      off       = (int*)(dinv + N);               // N+1
    char*     p         = align256((char*)(off + N + 1));
    unsigned* staging   = (unsigned*)p;                   // E * 4 B
    p = align256((char*)(staging + E));
    int*      esrc      = (int*)p;                        // E
    p = align256((char*)(esrc + E));
    __half*   xw1s      = (__half*)p;                     // N*64 fp16
    p = align256((char*)(xw1s + (size_t)N * NHID));
    __half*   h         = (__half*)p;                     // N*64 fp16
    p = align256((char*)(h + (size_t)N * NHID));
    float*    agg2      = (float*)p;                      // N*64 fp32
    p = align256((char*)(agg2 + (size_t)N * NHID));
    __half*   w1t       = (__half*)p;                     // 64*128 fp16

    hipMemsetAsync(gbhist, 0, (size_t)NB * sizeof(int), stream);

    long long perblk = (E + PBLK - 1) / PBLK;
    k_detect<<<1, 256, 0, stream>>>(ei, 4096, flag, W1, w1t);
    k_bhist<<<PBLK, 256, 0, stream>>>(ei, flag, E, gbhist, blockhist, NB, perblk);
    k_bscan<<<1, 256, 0, stream>>>(gbhist, NB, boff, bcur, off + N);
    k_partition<<<PBLK, 256, 0, stream>>>(ei, flag, E, bcur, blockhist, staging, NB, perblk);
    k_bucket<<<NB, 256, 0, stream>>>(staging, boff, N, off, esrc, dinv);

    k_gemm1<<<(N + 63) / 64, 256, 0, stream>>>(x, w1t, dinv, xw1s, N);

    k_agg1<<<(N + 3) / 4, 256, 0, stream>>>(off, esrc, dinv, (const uint4*)xw1s,
                                            b1, (uint4*)h, N);
    k_agg2<<<(N + 3) / 4, 256, 0, stream>>>(off, esrc, dinv, (const uint4*)h,
                                            agg2, N);

    int ntiles = (N + 63) / 64;
    int g2grid = ntiles < 768 ? ntiles : 768;
    k_gemm2<<<g2grid, 256, 0, stream>>>(agg2, W2, b2, out, N, ntiles);
}

// Round 2
// 304.399 us; speedup vs baseline: 1.1066x; 1.0315x over previous
//
#include <hip/hip_runtime.h>
#include <hip/hip_fp16.h>

#define NFEAT 128
#define NHID 64
#define MAXB 1024          // max dst buckets (node>>8), supports N<=262144
#define BSHIFT 8
#define BNODES 256
#define PBLK 512           // partition/hist blocks
#define DBINS 512          // degree bins for counting sort

typedef _Float16 f16x8 __attribute__((ext_vector_type(8)));
typedef float f32x4 __attribute__((ext_vector_type(4)));

// ---------- edge-index dtype detection + W1/W2 transpose/convert ----------
__global__ void k_detect(const int* __restrict__ ei_words, int nwords, int* flag,
                         const float* __restrict__ W1, __half* __restrict__ w1t,
                         const float* __restrict__ W2, __half* __restrict__ w2t) {
    __shared__ int s_or;
    if (threadIdx.x == 0) s_or = 0;
    __syncthreads();
    int acc = 0;
    for (int i = 1 + 2 * (int)threadIdx.x; i < nwords; i += 2 * (int)blockDim.x)
        acc |= ei_words[i];
    atomicOr(&s_or, acc);
    // W1[128][64] fp32 -> w1t[64][128] fp16
    for (int i = threadIdx.x; i < NFEAT * NHID; i += 256) {
        int n = i >> 7, k = i & 127;
        w1t[i] = __float2half(W1[k * NHID + n]);
    }
    // W2[64][128] fp32 -> w2t[128][64] fp16
    for (int i = threadIdx.x; i < NFEAT * NHID; i += 256) {
        int n = i >> 6, k = i & 63;
        w2t[i] = __float2half(W2[k * NFEAT + n]);
    }
    __syncthreads();
    if (threadIdx.x == 0) *flag = (s_or == 0) ? 1 : 0;
}

__device__ __forceinline__ int edge_idx(const int* __restrict__ ei, int is64,
                                        long long E, long long e, int which) {
    long long pos = which ? (E + e) : e;
    return is64 ? ei[2 * pos] : ei[pos];
}

// ---------- bucket histogram ----------
__global__ __launch_bounds__(256) void k_bhist(const int* __restrict__ ei,
                                               const int* __restrict__ flag,
                                               long long E, int* gbhist,
                                               int* __restrict__ blockhist,
                                               int NB, long long perblk) {
    __shared__ int hist[MAXB];
    for (int i = threadIdx.x; i < NB; i += 256) hist[i] = 0;
    __syncthreads();
    int is64 = *flag;
    long long lo = (long long)blockIdx.x * perblk;
    long long hi = lo + perblk; if (hi > E) hi = E;
    for (long long e = lo + threadIdx.x; e < hi; e += 256) {
        int d = edge_idx(ei, is64, E, e, 1);
        atomicAdd(&hist[d >> BSHIFT], 1);
    }
    __syncthreads();
    int* bh = blockhist + (size_t)blockIdx.x * MAXB;
    for (int i = threadIdx.x; i < NB; i += 256) {
        int v = hist[i];
        bh[i] = v;
        if (v) atomicAdd(&gbhist[i], v);
    }
}

// ---------- scan bucket totals (1 block); also writes off[N]=E ----------
__global__ __launch_bounds__(256) void k_bscan(const int* __restrict__ gbhist, int NB,
                                               int* boff, int* bcur, int* offN) {
    __shared__ int s[256];
    int t = threadIdx.x;
    int v[4]; int sum = 0;
#pragma unroll
    for (int j = 0; j < 4; ++j) {
        int i = t * 4 + j;
        v[j] = (i < NB) ? gbhist[i] : 0;
        sum += v[j];
    }
    s[t] = sum;
    __syncthreads();
    for (int d = 1; d < 256; d <<= 1) {
        int val = (t >= d) ? s[t - d] : 0;
        __syncthreads();
        s[t] += val;
        __syncthreads();
    }
    int run = s[t] - sum;   // exclusive
#pragma unroll
    for (int j = 0; j < 4; ++j) {
        int i = t * 4 + j;
        if (i <= NB) boff[i] = run;
        if (i < NB)  bcur[i] = run;
        run += v[j];
    }
    if (t == 255) *offN = s[255];   // off[N] = E
}

// ---------- partition edges into dst buckets ----------
__global__ __launch_bounds__(256) void k_partition(const int* __restrict__ ei,
                                                   const int* __restrict__ flag,
                                                   long long E, int* bcur,
                                                   const int* __restrict__ blockhist,
                                                   unsigned* __restrict__ staging,
                                                   int NB, long long perblk) {
    __shared__ int cur[MAXB];
    const int* bh = blockhist + (size_t)blockIdx.x * MAXB;
    for (int i = threadIdx.x; i < NB; i += 256) {
        int v = bh[i];
        cur[i] = v ? atomicAdd(&bcur[i], v) : 0;
    }
    __syncthreads();
    long long lo = (long long)blockIdx.x * perblk;
    long long hi = lo + perblk; if (hi > E) hi = E;
    int is64 = *flag;
    for (long long e = lo + threadIdx.x; e < hi; e += 256) {
        int s = edge_idx(ei, is64, E, e, 0);
        int d = edge_idx(ei, is64, E, e, 1);
        int pos = atomicAdd(&cur[d >> BSHIFT], 1);
        staging[pos] = (unsigned)s | ((unsigned)(d & (BNODES - 1)) << 24);
    }
}

// ---------- per-bucket CSR + degree histogram ----------
__global__ __launch_bounds__(256) void k_bucket(const unsigned* __restrict__ staging,
                                                const int* __restrict__ boff,
                                                int N, int* off, int* esrc, float* dinv,
                                                int* __restrict__ deghist) {
    __shared__ int cnt_s[BNODES];
    __shared__ int scan_s[BNODES];
    __shared__ int dh[DBINS];
    int b = blockIdx.x;
    int base = b << BSHIFT;
    int t = threadIdx.x;
    cnt_s[t] = 0;
    dh[t] = 0; dh[t + 256] = 0;
    __syncthreads();
    int lo = boff[b], hi = boff[b + 1];
    for (int e = lo + t; e < hi; e += 256)
        atomicAdd(&cnt_s[staging[e] >> 24], 1);
    __syncthreads();
    int v = cnt_s[t];
    scan_s[t] = v;
    __syncthreads();
    for (int d = 1; d < 256; d <<= 1) {
        int val = (t >= d) ? scan_s[t - d] : 0;
        __syncthreads();
        scan_s[t] += val;
        __syncthreads();
    }
    int excl = scan_s[t] - v;
    int node = base + t;
    if (node < N) {
        off[node] = lo + excl;
        dinv[node] = rsqrtf((float)v + 1.0f);   // +1 self loop
        atomicAdd(&dh[v < (DBINS - 1) ? v : (DBINS - 1)], 1);
    }
    __syncthreads();
    if (dh[t])       atomicAdd(&deghist[t], dh[t]);
    if (dh[t + 256]) atomicAdd(&deghist[t + 256], dh[t + 256]);
    cnt_s[t] = lo + excl;   // reuse as cursor
    __syncthreads();
    for (int e = lo + t; e < hi; e += 256) {
        unsigned sd = staging[e];
        int pos = atomicAdd(&cnt_s[sd >> 24], 1);
        esrc[pos] = (int)(sd & 0xFFFFFFu);
    }
}

// ---------- scan degree histogram (1 block, 512 bins) ----------
__global__ __launch_bounds__(256) void k_dscan(const int* __restrict__ deghist, int* dcur) {
    __shared__ int s[256];
    int t = threadIdx.x;
    int v0 = deghist[2 * t], v1 = deghist[2 * t + 1];
    int sum = v0 + v1;
    s[t] = sum;
    __syncthreads();
    for (int d = 1; d < 256; d <<= 1) {
        int val = (t >= d) ? s[t - d] : 0;
        __syncthreads();
        s[t] += val;
        __syncthreads();
    }
    int run = s[t] - sum;   // exclusive
    dcur[2 * t] = run;
    dcur[2 * t + 1] = run + v0;
}

// ---------- scatter nodes into degree-sorted perm (LDS-aggregated) ----------
__global__ __launch_bounds__(256) void k_dperm(const int* __restrict__ off, int* dcur,
                                               int* __restrict__ perm, int N) {
    __shared__ int cnt[DBINS];
    __shared__ int base[DBINS];
    int t = threadIdx.x;
    cnt[t] = 0; cnt[t + 256] = 0;
    __syncthreads();
    int n = blockIdx.x * 256 + t;
    int b = 0, myidx = 0;
    if (n < N) {
        int deg = off[n + 1] - off[n];
        b = deg < (DBINS - 1) ? deg : (DBINS - 1);
        myidx = atomicAdd(&cnt[b], 1);
    }
    __syncthreads();
    int c0 = cnt[t];       if (c0) base[t] = atomicAdd(&dcur[t], c0);
    int c1 = cnt[t + 256]; if (c1) base[t + 256] = atomicAdd(&dcur[t + 256], c1);
    __syncthreads();
    if (n < N) perm[base[b] + myidx] = n;
}

// ---------- LDS XOR-swizzles ----------
__device__ __forceinline__ int swz(int row, int byteoff) {      // 256 B row stride
    return (row << 8) + (byteoff ^ ((row & 7) << 4));
}
__device__ __forceinline__ int swz64(int row, int byteoff) {    // 128 B row stride
    return (row << 7) + (byteoff ^ ((row & 7) << 4));
}

// ---------- GEMM1 (MFMA): x[N,128]fp32 @ W1t -> dinv[row]*out, fp16 xw1s[N,64] ----------
__global__ __launch_bounds__(256) void k_gemm1(const float* __restrict__ x,
                                               const __half* __restrict__ w1t,
                                               const float* __restrict__ dinv,
                                               __half* __restrict__ xw1s, int N) {
    __shared__ __align__(16) __half xs[64 * NFEAT];  // 16 KB, swizzled
    __shared__ __align__(16) __half ws[NHID * NFEAT]; // 16 KB, swizzled
    int t = threadIdx.x;
    for (int i = t; i < NHID * NFEAT / 8; i += 256) {
        int row = i >> 4, c16 = (i & 15) << 4;
        uint4 v = ((const uint4*)w1t)[i];
        *(uint4*)((char*)ws + swz(row, c16)) = v;
    }
    int row0 = blockIdx.x * 64;
    for (int i = t; i < 64 * 32; i += 256) {
        int r = i >> 5, c4 = i & 31;
        int row = row0 + r;
        float4 v = (row < N) ? ((const float4*)x)[(size_t)row * 32 + c4]
                             : make_float4(0.f, 0.f, 0.f, 0.f);
        __half2 h0 = __floats2half2_rn(v.x, v.y);
        __half2 h1 = __floats2half2_rn(v.z, v.w);
        uint2 p = make_uint2(*(unsigned*)&h0, *(unsigned*)&h1);
        *(uint2*)((char*)xs + swz(r, c4 * 8)) = p;
    }
    __syncthreads();
    int wave = t >> 6, lane = t & 63;
    int lr = lane & 15, g = lane >> 4;
    int xrow = wave * 16 + lr;
    f16x8 xb[4];
#pragma unroll
    for (int kc = 0; kc < 4; ++kc)
        xb[kc] = *(const f16x8*)((const char*)xs + swz(xrow, kc * 64 + g * 16));
    int row = row0 + xrow;
    float di = (row < N) ? dinv[row] : 0.f;
#pragma unroll
    for (int c = 0; c < 4; ++c) {
        f32x4 acc = {0.f, 0.f, 0.f, 0.f};
#pragma unroll
        for (int kc = 0; kc < 4; ++kc) {
            f16x8 a = *(const f16x8*)((const char*)ws + swz(c * 16 + lr, kc * 64 + g * 16));
            acc = __builtin_amdgcn_mfma_f32_16x16x32_f16(a, xb[kc], acc, 0, 0, 0);
        }
        if (row < N) {
            __half2 o0 = __floats2half2_rn(di * acc[0], di * acc[1]);
            __half2 o1 = __floats2half2_rn(di * acc[2], di * acc[3]);
            uint2 p = make_uint2(*(unsigned*)&o0, *(unsigned*)&o1);
            *(uint2*)&xw1s[(size_t)row * NHID + c * 16 + g * 4] = p;
        }
    }
}

// ---------- group-per-node gather (reduction-free) ----------
__device__ __forceinline__ void addhalf8(float2 (&acc)[4], uint4 p) {
    const __half2* hh = (const __half2*)&p;
#pragma unroll
    for (int j = 0; j < 4; ++j) {
        float2 v = __half22float2(hh[j]);
        acc[j].x += v.x; acc[j].y += v.y;
    }
}

// 8-lane group g owns node d = perm[slot]; lane li accumulates 16B slice li.
__device__ __forceinline__ void gather_group(const int* __restrict__ off,
                                             const int* __restrict__ esrc,
                                             const uint4* __restrict__ feat4,
                                             int d, int li, int lo, int hi,
                                             float2 (&acc)[4]) {
#pragma unroll
    for (int j = 0; j < 4; ++j) acc[j] = make_float2(0.f, 0.f);
    int idx = (lo + li < hi) ? esrc[lo + li] : 0;   // prefetched chunk
    for (int e = lo; e < hi; e += 8) {
        int nrem = hi - e;
        int cur = idx;
        int ne = e + 8;
        idx = (ne + li < hi) ? esrc[ne + li] : 0;   // prefetch next chunk
        if (nrem >= 8) {
#pragma unroll
            for (int j = 0; j < 8; ++j) {
                int s = __shfl(cur, j, 8);
                addhalf8(acc, feat4[(size_t)s * 8 + li]);
            }
        } else {
            for (int j = 0; j < nrem; ++j) {
                int s = __shfl(cur, j, 8);
                addhalf8(acc, feat4[(size_t)s * 8 + li]);
            }
        }
    }
    addhalf8(acc, feat4[(size_t)d * 8 + li]);   // self loop (pre-scaled input)
}

// ---------- layer-1 aggregation: bias+relu, output pre-scaled fp16 h ----------
__global__ __launch_bounds__(256) void k_agg1(const int* __restrict__ off,
                                              const int* __restrict__ esrc,
                                              const int* __restrict__ perm,
                                              const float* __restrict__ dinv,
                                              const uint4* __restrict__ xw1s4,
                                              const float* __restrict__ b1,
                                              uint4* __restrict__ h4, int N) {
    int t = threadIdx.x;
    int lane = t & 63, wave = t >> 6;
    int g = lane >> 3, li = lane & 7;
    int slot = blockIdx.x * 32 + wave * 8 + g;
    bool valid = slot < N;
    int d  = valid ? perm[slot] : 0;
    int lo = valid ? off[d] : 0;
    int hi = valid ? off[d + 1] : 0;
    float2 acc[4];
    gather_group(off, esrc, xw1s4, d, li, lo, hi, acc);
    float dd = dinv[d];
    float4 bA = ((const float4*)b1)[li * 2 + 0];
    float4 bB = ((const float4*)b1)[li * 2 + 1];
    float v0 = fmaxf(dd * acc[0].x + bA.x, 0.f);
    float v1 = fmaxf(dd * acc[0].y + bA.y, 0.f);
    float v2 = fmaxf(dd * acc[1].x + bA.z, 0.f);
    float v3 = fmaxf(dd * acc[1].y + bA.w, 0.f);
    float v4 = fmaxf(dd * acc[2].x + bB.x, 0.f);
    float v5 = fmaxf(dd * acc[2].y + bB.y, 0.f);
    float v6 = fmaxf(dd * acc[3].x + bB.z, 0.f);
    float v7 = fmaxf(dd * acc[3].y + bB.w, 0.f);
    __half2 o[4];
    o[0] = __floats2half2_rn(dd * v0, dd * v1);   // pre-scaled for layer 2
    o[1] = __floats2half2_rn(dd * v2, dd * v3);
    o[2] = __floats2half2_rn(dd * v4, dd * v5);
    o[3] = __floats2half2_rn(dd * v6, dd * v7);
    if (valid) h4[(size_t)d * 8 + li] = *(const uint4*)o;
}

// ---------- layer-2 aggregation: fp16 in -> hi/lo fp16 planes ----------
__global__ __launch_bounds__(256) void k_agg2(const int* __restrict__ off,
                                              const int* __restrict__ esrc,
                                              const int* __restrict__ perm,
                                              const float* __restrict__ dinv,
                                              const uint4* __restrict__ h4,
                                              uint4* __restrict__ a2h,
                                              uint4* __restrict__ a2l, int N) {
    int t = threadIdx.x;
    int lane = t & 63, wave = t >> 6;
    int g = lane >> 3, li = lane & 7;
    int slot = blockIdx.x * 32 + wave * 8 + g;
    bool valid = slot < N;
    int d  = valid ? perm[slot] : 0;
    int lo = valid ? off[d] : 0;
    int hi = valid ? off[d + 1] : 0;
    float2 acc[4];
    gather_group(off, esrc, h4, d, li, lo, hi, acc);
    float dd = dinv[d];
    float v[8] = {dd * acc[0].x, dd * acc[0].y, dd * acc[1].x, dd * acc[1].y,
                  dd * acc[2].x, dd * acc[2].y, dd * acc[3].x, dd * acc[3].y};
    __half hh[8], ll[8];
#pragma unroll
    for (int j = 0; j < 8; ++j) {
        hh[j] = __float2half(v[j]);
        ll[j] = __float2half(v[j] - __half2float(hh[j]));
    }
    uint4 ph, pl;
    __half2* hp = (__half2*)&ph;
    __half2* lp = (__half2*)&pl;
#pragma unroll
    for (int j = 0; j < 4; ++j) {
        hp[j] = __halves2half2(hh[2 * j], hh[2 * j + 1]);
        lp[j] = __halves2half2(ll[2 * j], ll[2 * j + 1]);
    }
    if (valid) {
        a2h[(size_t)d * 8 + li] = ph;
        a2l[(size_t)d * 8 + li] = pl;
    }
}

// ---------- GEMM2 (MFMA, hi/lo split): agg2[N,64] @ W2[64,128] + b2 -> out fp32 ----------
__global__ __launch_bounds__(256) void k_gemm2(const __half* __restrict__ a2h,
                                               const __half* __restrict__ a2l,
                                               const __half* __restrict__ w2t,
                                               const float* __restrict__ b2,
                                               float* __restrict__ out, int N) {
    __shared__ __align__(16) __half sB[NFEAT * NHID]; // w2t 128x64, 16 KB swizzled
    __shared__ __align__(16) __half sH[64 * NHID];    // hi tile, 8 KB
    __shared__ __align__(16) __half sL[64 * NHID];    // lo tile, 8 KB
    int t = threadIdx.x;
    for (int i = t; i < NFEAT * NHID / 8; i += 256) {
        int row = i >> 3, c16 = (i & 7) << 4;
        uint4 v = ((const uint4*)w2t)[i];
        *(uint4*)((char*)sB + swz64(row, c16)) = v;
    }
    int row0 = blockIdx.x * 64;
    for (int i = t; i < 64 * 8; i += 256) {
        int r = i >> 3, c16 = (i & 7) << 4;
        int row = row0 + r;
        uint4 vh = make_uint4(0, 0, 0, 0), vl = make_uint4(0, 0, 0, 0);
        if (row < N) {
            vh = *(const uint4*)((const char*)a2h + (size_t)row * 128 + c16);
            vl = *(const uint4*)((const char*)a2l + (size_t)row * 128 + c16);
        }
        *(uint4*)((char*)sH + swz64(r, c16)) = vh;
        *(uint4*)((char*)sL + swz64(r, c16)) = vl;
    }
    __syncthreads();
    int wave = t >> 6, lane = t & 63;
    int lr = lane & 15, g = lane >> 4;
    int xrow = wave * 16 + lr;
    f16x8 xh[2], xl[2];
#pragma unroll
    for (int kc = 0; kc < 2; ++kc) {
        xh[kc] = *(const f16x8*)((const char*)sH + swz64(xrow, kc * 64 + g * 16));
        xl[kc] = *(const f16x8*)((const char*)sL + swz64(xrow, kc * 64 + g * 16));
    }
    int row = row0 + xrow;
#pragma unroll
    for (int c = 0; c < 8; ++c) {
        f32x4 acc = {0.f, 0.f, 0.f, 0.f};
#pragma unroll
        for (int kc = 0; kc < 2; ++kc) {
            f16x8 a = *(const f16x8*)((const char*)sB + swz64(c * 16 + lr, kc * 64 + g * 16));
            acc = __builtin_amdgcn_mfma_f32_16x16x32_f16(a, xl[kc], acc, 0, 0, 0);
            acc = __builtin_amdgcn_mfma_f32_16x16x32_f16(a, xh[kc], acc, 0, 0, 0);
        }
        if (row < N) {
            float4 bb = *(const float4*)&b2[c * 16 + g * 4];
            float4 o = make_float4(acc[0] + bb.x, acc[1] + bb.y,
                                   acc[2] + bb.z, acc[3] + bb.w);
            *(float4*)&out[(size_t)row * NFEAT + c * 16 + g * 4] = o;
        }
    }
}

static inline char* align256(char* p) {
    return (char*)(((uintptr_t)p + 255) & ~(uintptr_t)255);
}

extern "C" void kernel_launch(void* const* d_in, const int* in_sizes, int n_in,
                              void* d_out, int out_size, void* d_ws, size_t ws_size,
                              hipStream_t stream) {
    const float* x  = (const float*)d_in[0];
    const int*   ei = (const int*)d_in[1];
    const float* W1 = (const float*)d_in[2];
    const float* b1 = (const float*)d_in[3];
    const float* W2 = (const float*)d_in[4];
    const float* b2 = (const float*)d_in[5];
    float* out = (float*)d_out;

    const int N = in_sizes[0] / NFEAT;            // 100000
    const long long E = in_sizes[1] / 2;          // 1600000
    const int NB = (N + BNODES - 1) >> BSHIFT;    // 391 buckets

    // workspace layout
    char* w = (char*)d_ws;
    int*      flag      = (int*)w;                        // pad 256 B
    int*      gbhist    = (int*)(w + 256);                // MAXB
    int*      boff      = gbhist + MAXB;                  // MAXB+1
    int*      bcur      = boff + MAXB + 1;                // MAXB
    int*      deghist   = bcur + MAXB;                    // DBINS
    int*      dcur      = deghist + DBINS;                // DBINS
    int*      blockhist = dcur + DBINS;                   // PBLK*MAXB (2 MB)
    float*    dinv      = (float*)(blockhist + (size_t)PBLK * MAXB);  // N
    int*      off       = (int*)(dinv + N);               // N+1
    int*      perm      = off + N + 1;                    // N
    char*     p         = align256((char*)(perm + N));
    unsigned* staging   = (unsigned*)p;                   // E * 4 B
    p = align256((char*)(staging + E));
    int*      esrc      = (int*)p;                        // E
    p = align256((char*)(esrc + E));
    __half*   xw1s      = (__half*)p;                     // N*64 fp16
    p = align256((char*)(xw1s + (size_t)N * NHID));
    __half*   h         = (__half*)p;                     // N*64 fp16
    p = align256((char*)(h + (size_t)N * NHID));
    __half*   a2h       = (__half*)p;                     // N*64 fp16
    p = align256((char*)(a2h + (size_t)N * NHID));
    __half*   a2l       = (__half*)p;                     // N*64 fp16
    p = align256((char*)(a2l + (size_t)N * NHID));
    __half*   w1t       = (__half*)p;                     // 64*128 fp16
    p = align256((char*)(w1t + NFEAT * NHID));
    __half*   w2t       = (__half*)p;                     // 128*64 fp16

    hipMemsetAsync(gbhist, 0, (size_t)NB * sizeof(int), stream);
    hipMemsetAsync(deghist, 0, (size_t)DBINS * sizeof(int), stream);

    long long perblk = (E + PBLK - 1) / PBLK;
    k_detect<<<1, 256, 0, stream>>>(ei, 4096, flag, W1, w1t, W2, w2t);
    k_bhist<<<PBLK, 256, 0, stream>>>(ei, flag, E, gbhist, blockhist, NB, perblk);
    k_bscan<<<1, 256, 0, stream>>>(gbhist, NB, boff, bcur, off + N);
    k_partition<<<PBLK, 256, 0, stream>>>(ei, flag, E, bcur, blockhist, staging, NB, perblk);
    k_bucket<<<NB, 256, 0, stream>>>(staging, boff, N, off, esrc, dinv, deghist);
    k_dscan<<<1, 256, 0, stream>>>(deghist, dcur);
    k_dperm<<<(N + 255) / 256, 256, 0, stream>>>(off, dcur, perm, N);

    k_gemm1<<<(N + 63) / 64, 256, 0, stream>>>(x, w1t, dinv, xw1s, N);

    k_agg1<<<(N + 31) / 32, 256, 0, stream>>>(off, esrc, perm, dinv, (const uint4*)xw1s,
                                              b1, (uint4*)h, N);
    k_agg2<<<(N + 31) / 32, 256, 0, stream>>>(off, esrc, perm, dinv, (const uint4*)h,
                                              (uint4*)a2h, (uint4*)a2l, N);

    k_gemm2<<<(N + 63) / 64, 256, 0, stream>>>(a2h, a2l, w2t, b2, out, N);
}

// Round 3
// 303.792 us; speedup vs baseline: 1.1089x; 1.0020x over previous
//
#include <hip/hip_runtime.h>
#include <hip/hip_fp16.h>

#define NFEAT 128
#define NHID 64
#define MAXB 1024          // max dst buckets (node>>8), supports N<=262144
#define BSHIFT 8
#define BNODES 256
#define PBLK 512           // partition/hist blocks
#define DBINS 512          // degree bins for counting sort

typedef _Float16 f16x8 __attribute__((ext_vector_type(8)));
typedef float f32x4 __attribute__((ext_vector_type(4)));

// ---------- edge-index dtype detection + W1/W2 transpose/convert ----------
__global__ void k_detect(const int* __restrict__ ei_words, int nwords, int* flag,
                         const float* __restrict__ W1, __half* __restrict__ w1t,
                         const float* __restrict__ W2, __half* __restrict__ w2t) {
    __shared__ int s_or;
    if (threadIdx.x == 0) s_or = 0;
    __syncthreads();
    int acc = 0;
    for (int i = 1 + 2 * (int)threadIdx.x; i < nwords; i += 2 * (int)blockDim.x)
        acc |= ei_words[i];
    atomicOr(&s_or, acc);
    // W1[128][64] fp32 -> w1t[64][128] fp16
    for (int i = threadIdx.x; i < NFEAT * NHID; i += 256) {
        int n = i >> 7, k = i & 127;
        w1t[i] = __float2half(W1[k * NHID + n]);
    }
    // W2[64][128] fp32 -> w2t[128][64] fp16
    for (int i = threadIdx.x; i < NFEAT * NHID; i += 256) {
        int n = i >> 6, k = i & 63;
        w2t[i] = __float2half(W2[k * NFEAT + n]);
    }
    __syncthreads();
    if (threadIdx.x == 0) *flag = (s_or == 0) ? 1 : 0;
}

__device__ __forceinline__ int edge_idx(const int* __restrict__ ei, int is64,
                                        long long E, long long e, int which) {
    long long pos = which ? (E + e) : e;
    return is64 ? ei[2 * pos] : ei[pos];
}

// load 8 consecutive edge indices (one array: base points at src or dst array)
__device__ __forceinline__ void load8(const int* __restrict__ ei, int is64,
                                      long long E, long long e0, int which,
                                      int (&v)[8]) {
    if (is64) {
        const int* base = ei + 2 * (which ? E + e0 : e0);
        int4 a = *(const int4*)(base + 0);
        int4 b = *(const int4*)(base + 4);
        int4 c = *(const int4*)(base + 8);
        int4 d = *(const int4*)(base + 12);
        v[0] = a.x; v[1] = a.z; v[2] = b.x; v[3] = b.z;
        v[4] = c.x; v[5] = c.z; v[6] = d.x; v[7] = d.z;
    } else {
        const int* base = ei + (which ? E + e0 : e0);
        int4 a = *(const int4*)(base + 0);
        int4 b = *(const int4*)(base + 4);
        v[0] = a.x; v[1] = a.y; v[2] = a.z; v[3] = a.w;
        v[4] = b.x; v[5] = b.y; v[6] = b.z; v[7] = b.w;
    }
}

// ---------- bucket histogram (8 edges/thread/iter, vectorized loads) ----------
__global__ __launch_bounds__(256) void k_bhist(const int* __restrict__ ei,
                                               const int* __restrict__ flag,
                                               long long E, int* gbhist,
                                               int* __restrict__ blockhist,
                                               int NB, long long perblk) {
    __shared__ int hist[MAXB];
    for (int i = threadIdx.x; i < NB; i += 256) hist[i] = 0;
    __syncthreads();
    int is64 = *flag;
    long long lo = (long long)blockIdx.x * perblk;
    long long hi = lo + perblk; if (hi > E) hi = E;
    for (long long e0 = lo + (long long)threadIdx.x * 8; e0 + 8 <= hi; e0 += 256 * 8) {
        int d[8];
        load8(ei, is64, E, e0, 1, d);
#pragma unroll
        for (int j = 0; j < 8; ++j)
            atomicAdd(&hist[d[j] >> BSHIFT], 1);
    }
    long long tail = lo + ((hi - lo) & ~7LL);
    for (long long e = tail + threadIdx.x; e < hi; e += 256) {
        int d = edge_idx(ei, is64, E, e, 1);
        atomicAdd(&hist[d >> BSHIFT], 1);
    }
    __syncthreads();
    int* bh = blockhist + (size_t)blockIdx.x * MAXB;
    for (int i = threadIdx.x; i < NB; i += 256) {
        int v = hist[i];
        bh[i] = v;
        if (v) atomicAdd(&gbhist[i], v);
    }
}

// ---------- scan bucket totals (1 block); also writes off[N]=E ----------
__global__ __launch_bounds__(256) void k_bscan(const int* __restrict__ gbhist, int NB,
                                               int* boff, int* bcur, int* offN) {
    __shared__ int s[256];
    int t = threadIdx.x;
    int v[4]; int sum = 0;
#pragma unroll
    for (int j = 0; j < 4; ++j) {
        int i = t * 4 + j;
        v[j] = (i < NB) ? gbhist[i] : 0;
        sum += v[j];
    }
    s[t] = sum;
    __syncthreads();
    for (int d = 1; d < 256; d <<= 1) {
        int val = (t >= d) ? s[t - d] : 0;
        __syncthreads();
        s[t] += val;
        __syncthreads();
    }
    int run = s[t] - sum;   // exclusive
#pragma unroll
    for (int j = 0; j < 4; ++j) {
        int i = t * 4 + j;
        if (i <= NB) boff[i] = run;
        if (i < NB)  bcur[i] = run;
        run += v[j];
    }
    if (t == 255) *offN = s[255];   // off[N] = E
}

// ---------- partition edges into dst buckets (8 edges/thread/iter) ----------
__global__ __launch_bounds__(256) void k_partition(const int* __restrict__ ei,
                                                   const int* __restrict__ flag,
                                                   long long E, int* bcur,
                                                   const int* __restrict__ blockhist,
                                                   unsigned* __restrict__ staging,
                                                   int NB, long long perblk) {
    __shared__ int cur[MAXB];
    const int* bh = blockhist + (size_t)blockIdx.x * MAXB;
    for (int i = threadIdx.x; i < NB; i += 256) {
        int v = bh[i];
        cur[i] = v ? atomicAdd(&bcur[i], v) : 0;
    }
    __syncthreads();
    long long lo = (long long)blockIdx.x * perblk;
    long long hi = lo + perblk; if (hi > E) hi = E;
    int is64 = *flag;
    for (long long e0 = lo + (long long)threadIdx.x * 8; e0 + 8 <= hi; e0 += 256 * 8) {
        int s[8], d[8];
        load8(ei, is64, E, e0, 0, s);
        load8(ei, is64, E, e0, 1, d);
#pragma unroll
        for (int j = 0; j < 8; ++j) {
            int pos = atomicAdd(&cur[d[j] >> BSHIFT], 1);
            staging[pos] = (unsigned)s[j] | ((unsigned)(d[j] & (BNODES - 1)) << 24);
        }
    }
    long long tail = lo + ((hi - lo) & ~7LL);
    for (long long e = tail + threadIdx.x; e < hi; e += 256) {
        int s = edge_idx(ei, is64, E, e, 0);
        int d = edge_idx(ei, is64, E, e, 1);
        int pos = atomicAdd(&cur[d >> BSHIFT], 1);
        staging[pos] = (unsigned)s | ((unsigned)(d & (BNODES - 1)) << 24);
    }
}

// ---------- per-bucket CSR + degree histogram ----------
__global__ __launch_bounds__(256) void k_bucket(const unsigned* __restrict__ staging,
                                                const int* __restrict__ boff,
                                                int N, int* off, int* esrc, float* dinv,
                                                int* __restrict__ deghist) {
    __shared__ int cnt_s[BNODES];
    __shared__ int scan_s[BNODES];
    __shared__ int dh[DBINS];
    int b = blockIdx.x;
    int base = b << BSHIFT;
    int t = threadIdx.x;
    cnt_s[t] = 0;
    dh[t] = 0; dh[t + 256] = 0;
    __syncthreads();
    int lo = boff[b], hi = boff[b + 1];
    for (int e = lo + t; e < hi; e += 256)
        atomicAdd(&cnt_s[staging[e] >> 24], 1);
    __syncthreads();
    int v = cnt_s[t];
    scan_s[t] = v;
    __syncthreads();
    for (int d = 1; d < 256; d <<= 1) {
        int val = (t >= d) ? scan_s[t - d] : 0;
        __syncthreads();
        scan_s[t] += val;
        __syncthreads();
    }
    int excl = scan_s[t] - v;
    int node = base + t;
    if (node < N) {
        off[node] = lo + excl;
        dinv[node] = rsqrtf((float)v + 1.0f);   // +1 self loop
        atomicAdd(&dh[v < (DBINS - 1) ? v : (DBINS - 1)], 1);
    }
    __syncthreads();
    if (dh[t])       atomicAdd(&deghist[t], dh[t]);
    if (dh[t + 256]) atomicAdd(&deghist[t + 256], dh[t + 256]);
    cnt_s[t] = lo + excl;   // reuse as cursor
    __syncthreads();
    for (int e = lo + t; e < hi; e += 256) {
        unsigned sd = staging[e];
        int pos = atomicAdd(&cnt_s[sd >> 24], 1);
        esrc[pos] = (int)(sd & 0xFFFFFFu);
    }
}

// ---------- scan degree histogram (1 block, 512 bins) ----------
__global__ __launch_bounds__(256) void k_dscan(const int* __restrict__ deghist, int* dcur) {
    __shared__ int s[256];
    int t = threadIdx.x;
    int v0 = deghist[2 * t], v1 = deghist[2 * t + 1];
    int sum = v0 + v1;
    s[t] = sum;
    __syncthreads();
    for (int d = 1; d < 256; d <<= 1) {
        int val = (t >= d) ? s[t - d] : 0;
        __syncthreads();
        s[t] += val;
        __syncthreads();
    }
    int run = s[t] - sum;   // exclusive
    dcur[2 * t] = run;
    dcur[2 * t + 1] = run + v0;
}

// ---------- scatter nodes into degree-sorted perm (LDS-aggregated) ----------
__global__ __launch_bounds__(256) void k_dperm(const int* __restrict__ off, int* dcur,
                                               int* __restrict__ perm, int N) {
    __shared__ int cnt[DBINS];
    __shared__ int base[DBINS];
    int t = threadIdx.x;
    cnt[t] = 0; cnt[t + 256] = 0;
    __syncthreads();
    int n = blockIdx.x * 256 + t;
    int b = 0, myidx = 0;
    if (n < N) {
        int deg = off[n + 1] - off[n];
        b = deg < (DBINS - 1) ? deg : (DBINS - 1);
        myidx = atomicAdd(&cnt[b], 1);
    }
    __syncthreads();
    int c0 = cnt[t];       if (c0) base[t] = atomicAdd(&dcur[t], c0);
    int c1 = cnt[t + 256]; if (c1) base[t + 256] = atomicAdd(&dcur[t + 256], c1);
    __syncthreads();
    if (n < N) perm[base[b] + myidx] = n;
}

// ---------- LDS XOR-swizzles ----------
__device__ __forceinline__ int swz(int row, int byteoff) {      // 256 B row stride
    return (row << 8) + (byteoff ^ ((row & 7) << 4));
}
__device__ __forceinline__ int swz64(int row, int byteoff) {    // 128 B row stride
    return (row << 7) + (byteoff ^ ((row & 7) << 4));
}

// ---------- GEMM1 (MFMA): x[N,128]fp32 @ W1t -> dinv[row]*out, fp16 xw1s[N,64] ----------
__global__ __launch_bounds__(256) void k_gemm1(const float* __restrict__ x,
                                               const __half* __restrict__ w1t,
                                               const float* __restrict__ dinv,
                                               __half* __restrict__ xw1s, int N) {
    __shared__ __align__(16) __half xs[64 * NFEAT];  // 16 KB, swizzled
    __shared__ __align__(16) __half ws[NHID * NFEAT]; // 16 KB, swizzled
    int t = threadIdx.x;
    for (int i = t; i < NHID * NFEAT / 8; i += 256) {
        int row = i >> 4, c16 = (i & 15) << 4;
        uint4 v = ((const uint4*)w1t)[i];
        *(uint4*)((char*)ws + swz(row, c16)) = v;
    }
    int row0 = blockIdx.x * 64;
    for (int i = t; i < 64 * 32; i += 256) {
        int r = i >> 5, c4 = i & 31;
        int row = row0 + r;
        float4 v = (row < N) ? ((const float4*)x)[(size_t)row * 32 + c4]
                             : make_float4(0.f, 0.f, 0.f, 0.f);
        __half2 h0 = __floats2half2_rn(v.x, v.y);
        __half2 h1 = __floats2half2_rn(v.z, v.w);
        uint2 p = make_uint2(*(unsigned*)&h0, *(unsigned*)&h1);
        *(uint2*)((char*)xs + swz(r, c4 * 8)) = p;
    }
    __syncthreads();
    int wave = t >> 6, lane = t & 63;
    int lr = lane & 15, g = lane >> 4;
    int xrow = wave * 16 + lr;
    f16x8 xb[4];
#pragma unroll
    for (int kc = 0; kc < 4; ++kc)
        xb[kc] = *(const f16x8*)((const char*)xs + swz(xrow, kc * 64 + g * 16));
    int row = row0 + xrow;
    float di = (row < N) ? dinv[row] : 0.f;
#pragma unroll
    for (int c = 0; c < 4; ++c) {
        f32x4 acc = {0.f, 0.f, 0.f, 0.f};
#pragma unroll
        for (int kc = 0; kc < 4; ++kc) {
            f16x8 a = *(const f16x8*)((const char*)ws + swz(c * 16 + lr, kc * 64 + g * 16));
            acc = __builtin_amdgcn_mfma_f32_16x16x32_f16(a, xb[kc], acc, 0, 0, 0);
        }
        if (row < N) {
            __half2 o0 = __floats2half2_rn(di * acc[0], di * acc[1]);
            __half2 o1 = __floats2half2_rn(di * acc[2], di * acc[3]);
            uint2 p = make_uint2(*(unsigned*)&o0, *(unsigned*)&o1);
            *(uint2*)&xw1s[(size_t)row * NHID + c * 16 + g * 4] = p;
        }
    }
}

// ---------- group-per-node gather (reduction-free) ----------
__device__ __forceinline__ void addhalf8(float2 (&acc)[4], uint4 p) {
    const __half2* hh = (const __half2*)&p;
#pragma unroll
    for (int j = 0; j < 4; ++j) {
        float2 v = __half22float2(hh[j]);
        acc[j].x += v.x; acc[j].y += v.y;
    }
}

// 8-lane group g owns node d = perm[slot]; lane li accumulates 16B slice li.
__device__ __forceinline__ void gather_group(const int* __restrict__ off,
                                             const int* __restrict__ esrc,
                                             const uint4* __restrict__ feat4,
                                             int d, int li, int lo, int hi,
                                             float2 (&acc)[4]) {
#pragma unroll
    for (int j = 0; j < 4; ++j) acc[j] = make_float2(0.f, 0.f);
    int idx = (lo + li < hi) ? esrc[lo + li] : 0;   // prefetched chunk
    for (int e = lo; e < hi; e += 8) {
        int nrem = hi - e;
        int cur = idx;
        int ne = e + 8;
        idx = (ne + li < hi) ? esrc[ne + li] : 0;   // prefetch next chunk
        if (nrem >= 8) {
#pragma unroll
            for (int j = 0; j < 8; ++j) {
                int s = __shfl(cur, j, 8);
                addhalf8(acc, feat4[(size_t)s * 8 + li]);
            }
        } else {
            for (int j = 0; j < nrem; ++j) {
                int s = __shfl(cur, j, 8);
                addhalf8(acc, feat4[(size_t)s * 8 + li]);
            }
        }
    }
    addhalf8(acc, feat4[(size_t)d * 8 + li]);   // self loop (pre-scaled input)
}

// ---------- layer-1 aggregation: bias+relu, output pre-scaled fp16 h ----------
__global__ __launch_bounds__(256) void k_agg1(const int* __restrict__ off,
                                              const int* __restrict__ esrc,
                                              const int* __restrict__ perm,
                                              const float* __restrict__ dinv,
                                              const uint4* __restrict__ xw1s4,
                                              const float* __restrict__ b1,
                                              uint4* __restrict__ h4, int N) {
    int t = threadIdx.x;
    int lane = t & 63, wave = t >> 6;
    int g = lane >> 3, li = lane & 7;
    int slot = blockIdx.x * 32 + wave * 8 + g;
    bool valid = slot < N;
    int d  = valid ? perm[slot] : 0;
    int lo = valid ? off[d] : 0;
    int hi = valid ? off[d + 1] : 0;
    float2 acc[4];
    gather_group(off, esrc, xw1s4, d, li, lo, hi, acc);
    float dd = dinv[d];
    float4 bA = ((const float4*)b1)[li * 2 + 0];
    float4 bB = ((const float4*)b1)[li * 2 + 1];
    float v0 = fmaxf(dd * acc[0].x + bA.x, 0.f);
    float v1 = fmaxf(dd * acc[0].y + bA.y, 0.f);
    float v2 = fmaxf(dd * acc[1].x + bA.z, 0.f);
    float v3 = fmaxf(dd * acc[1].y + bA.w, 0.f);
    float v4 = fmaxf(dd * acc[2].x + bB.x, 0.f);
    float v5 = fmaxf(dd * acc[2].y + bB.y, 0.f);
    float v6 = fmaxf(dd * acc[3].x + bB.z, 0.f);
    float v7 = fmaxf(dd * acc[3].y + bB.w, 0.f);
    __half2 o[4];
    o[0] = __floats2half2_rn(dd * v0, dd * v1);   // pre-scaled for layer 2
    o[1] = __floats2half2_rn(dd * v2, dd * v3);
    o[2] = __floats2half2_rn(dd * v4, dd * v5);
    o[3] = __floats2half2_rn(dd * v6, dd * v7);
    if (valid) h4[(size_t)d * 8 + li] = *(const uint4*)o;
}

// ---------- layer-2 aggregation: fp16 in -> hi/lo fp16 planes ----------
__global__ __launch_bounds__(256) void k_agg2(const int* __restrict__ off,
                                              const int* __restrict__ esrc,
                                              const int* __restrict__ perm,
                                              const float* __restrict__ dinv,
                                              const uint4* __restrict__ h4,
                                              uint4* __restrict__ a2h,
                                              uint4* __restrict__ a2l, int N) {
    int t = threadIdx.x;
    int lane = t & 63, wave = t >> 6;
    int g = lane >> 3, li = lane & 7;
    int slot = blockIdx.x * 32 + wave * 8 + g;
    bool valid = slot < N;
    int d  = valid ? perm[slot] : 0;
    int lo = valid ? off[d] : 0;
    int hi = valid ? off[d + 1] : 0;
    float2 acc[4];
    gather_group(off, esrc, h4, d, li, lo, hi, acc);
    float dd = dinv[d];
    float v[8] = {dd * acc[0].x, dd * acc[0].y, dd * acc[1].x, dd * acc[1].y,
                  dd * acc[2].x, dd * acc[2].y, dd * acc[3].x, dd * acc[3].y};
    __half hh[8], ll[8];
#pragma unroll
    for (int j = 0; j < 8; ++j) {
        hh[j] = __float2half(v[j]);
        ll[j] = __float2half(v[j] - __half2float(hh[j]));
    }
    uint4 ph, pl;
    __half2* hp = (__half2*)&ph;
    __half2* lp = (__half2*)&pl;
#pragma unroll
    for (int j = 0; j < 4; ++j) {
        hp[j] = __halves2half2(hh[2 * j], hh[2 * j + 1]);
        lp[j] = __halves2half2(ll[2 * j], ll[2 * j + 1]);
    }
    if (valid) {
        a2h[(size_t)d * 8 + li] = ph;
        a2l[(size_t)d * 8 + li] = pl;
    }
}

// ---------- GEMM2 (MFMA, hi/lo split): agg2[N,64] @ W2[64,128] + b2 -> out fp32 ----------
__global__ __launch_bounds__(256) void k_gemm2(const __half* __restrict__ a2h,
                                               const __half* __restrict__ a2l,
                                               const __half* __restrict__ w2t,
                                               const float* __restrict__ b2,
                                               float* __restrict__ out, int N) {
    __shared__ __align__(16) __half sB[NFEAT * NHID]; // w2t 128x64, 16 KB swizzled
    __shared__ __align__(16) __half sH[64 * NHID];    // hi tile, 8 KB
    __shared__ __align__(16) __half sL[64 * NHID];    // lo tile, 8 KB
    int t = threadIdx.x;
    for (int i = t; i < NFEAT * NHID / 8; i += 256) {
        int row = i >> 3, c16 = (i & 7) << 4;
        uint4 v = ((const uint4*)w2t)[i];
        *(uint4*)((char*)sB + swz64(row, c16)) = v;
    }
    int row0 = blockIdx.x * 64;
    for (int i = t; i < 64 * 8; i += 256) {
        int r = i >> 3, c16 = (i & 7) << 4;
        int row = row0 + r;
        uint4 vh = make_uint4(0, 0, 0, 0), vl = make_uint4(0, 0, 0, 0);
        if (row < N) {
            vh = *(const uint4*)((const char*)a2h + (size_t)row * 128 + c16);
            vl = *(const uint4*)((const char*)a2l + (size_t)row * 128 + c16);
        }
        *(uint4*)((char*)sH + swz64(r, c16)) = vh;
        *(uint4*)((char*)sL + swz64(r, c16)) = vl;
    }
    __syncthreads();
    int wave = t >> 6, lane = t & 63;
    int lr = lane & 15, g = lane >> 4;
    int xrow = wave * 16 + lr;
    f16x8 xh[2], xl[2];
#pragma unroll
    for (int kc = 0; kc < 2; ++kc) {
        xh[kc] = *(const f16x8*)((const char*)sH + swz64(xrow, kc * 64 + g * 16));
        xl[kc] = *(const f16x8*)((const char*)sL + swz64(xrow, kc * 64 + g * 16));
    }
    int row = row0 + xrow;
#pragma unroll
    for (int c = 0; c < 8; ++c) {
        f32x4 acc = {0.f, 0.f, 0.f, 0.f};
#pragma unroll
        for (int kc = 0; kc < 2; ++kc) {
            f16x8 a = *(const f16x8*)((const char*)sB + swz64(c * 16 + lr, kc * 64 + g * 16));
            acc = __builtin_amdgcn_mfma_f32_16x16x32_f16(a, xl[kc], acc, 0, 0, 0);
            acc = __builtin_amdgcn_mfma_f32_16x16x32_f16(a, xh[kc], acc, 0, 0, 0);
        }
        if (row < N) {
            float4 bb = *(const float4*)&b2[c * 16 + g * 4];
            float4 o = make_float4(acc[0] + bb.x, acc[1] + bb.y,
                                   acc[2] + bb.z, acc[3] + bb.w);
            *(float4*)&out[(size_t)row * NFEAT + c * 16 + g * 4] = o;
        }
    }
}

static inline char* align256(char* p) {
    return (char*)(((uintptr_t)p + 255) & ~(uintptr_t)255);
}

extern "C" void kernel_launch(void* const* d_in, const int* in_sizes, int n_in,
                              void* d_out, int out_size, void* d_ws, size_t ws_size,
                              hipStream_t stream) {
    const float* x  = (const float*)d_in[0];
    const int*   ei = (const int*)d_in[1];
    const float* W1 = (const float*)d_in[2];
    const float* b1 = (const float*)d_in[3];
    const float* W2 = (const float*)d_in[4];
    const float* b2 = (const float*)d_in[5];
    float* out = (float*)d_out;

    const int N = in_sizes[0] / NFEAT;            // 100000
    const long long E = in_sizes[1] / 2;          // 1600000
    const int NB = (N + BNODES - 1) >> BSHIFT;    // 391 buckets

    // workspace layout
    char* w = (char*)d_ws;
    int*      flag      = (int*)w;                        // pad 256 B
    int*      gbhist    = (int*)(w + 256);                // MAXB
    int*      boff      = gbhist + MAXB;                  // MAXB+1
    int*      bcur      = boff + MAXB + 1;                // MAXB
    int*      deghist   = bcur + MAXB;                    // DBINS
    int*      dcur      = deghist + DBINS;                // DBINS
    int*      blockhist = dcur + DBINS;                   // PBLK*MAXB (2 MB)
    float*    dinv      = (float*)(blockhist + (size_t)PBLK * MAXB);  // N
    int*      off       = (int*)(dinv + N);               // N+1
    int*      perm      = off + N + 1;                    // N
    char*     p         = align256((char*)(perm + N));
    unsigned* staging   = (unsigned*)p;                   // E * 4 B
    p = align256((char*)(staging + E));
    int*      esrc      = (int*)p;                        // E
    p = align256((char*)(esrc + E));
    __half*   xw1s      = (__half*)p;                     // N*64 fp16
    p = align256((char*)(xw1s + (size_t)N * NHID));
    __half*   h         = (__half*)p;                     // N*64 fp16
    p = align256((char*)(h + (size_t)N * NHID));
    __half*   a2h       = (__half*)p;                     // N*64 fp16
    p = align256((char*)(a2h + (size_t)N * NHID));
    __half*   a2l       = (__half*)p;                     // N*64 fp16
    p = align256((char*)(a2l + (size_t)N * NHID));
    __half*   w1t       = (__half*)p;                     // 64*128 fp16
    p = align256((char*)(w1t + NFEAT * NHID));
    __half*   w2t       = (__half*)p;                     // 128*64 fp16

    hipMemsetAsync(gbhist, 0, (size_t)NB * sizeof(int), stream);
    hipMemsetAsync(deghist, 0, (size_t)DBINS * sizeof(int), stream);

    long long perblk = ((E + PBLK - 1) / PBLK + 7) & ~7LL;   // multiple of 8
    k_detect<<<1, 256, 0, stream>>>(ei, 4096, flag, W1, w1t, W2, w2t);
    k_bhist<<<PBLK, 256, 0, stream>>>(ei, flag, E, gbhist, blockhist, NB, perblk);
    k_bscan<<<1, 256, 0, stream>>>(gbhist, NB, boff, bcur, off + N);
    k_partition<<<PBLK, 256, 0, stream>>>(ei, flag, E, bcur, blockhist, staging, NB, perblk);
    k_bucket<<<NB, 256, 0, stream>>>(staging, boff, N, off, esrc, dinv, deghist);
    k_dscan<<<1, 256, 0, stream>>>(deghist, dcur);
    k_dperm<<<(N + 255) / 256, 256, 0, stream>>>(off, dcur, perm, N);

    k_gemm1<<<(N + 63) / 64, 256, 0, stream>>>(x, w1t, dinv, xw1s, N);

    k_agg1<<<(N + 31) / 32, 256, 0, stream>>>(off, esrc, perm, dinv, (const uint4*)xw1s,
                                              b1, (uint4*)h, N);
    k_agg2<<<(N + 31) / 32, 256, 0, stream>>>(off, esrc, perm, dinv, (const uint4*)h,
                                              (uint4*)a2h, (uint4*)a2l, N);

    k_gemm2<<<(N + 63) / 64, 256, 0, stream>>>(a2h, a2l, w2t, b2, out, N);
}